// Round 4
// baseline (949.698 us; speedup 1.0000x reference)
//
#include <hip/hip_runtime.h>
#include <hip/hip_bf16.h>
#include <stdint.h>

typedef unsigned short u16;
typedef __attribute__((ext_vector_type(8))) short short8;
typedef __attribute__((ext_vector_type(4))) float f32x4;

#define NB 64
#define NN 4096
#define NS 8
#define ND 256
#define GROWS (NB*NN)   // 262144

__device__ inline u16 f2bf(float f) {
    uint32_t u = __float_as_uint(f);
    u = (u + 0x7FFFu + ((u >> 16) & 1u)) >> 16;
    return (u16)u;
}
__device__ inline float bf2f(u16 h) {
    return __uint_as_float(((uint32_t)h) << 16);
}
__device__ inline f32x4 mfma16(short8 a, short8 b, f32x4 c) {
    return __builtin_amdgcn_mfma_f32_16x16x32_bf16(a, b, c, 0, 0, 0);
}

// ---------------- weight conversion fp32 -> bf16 (once per launch) ----------
__global__ __launch_bounds__(256) void prep_w(
        const float* __restrict__ wk, const float* __restrict__ wv, const float* __restrict__ wq,
        const float* __restrict__ wih, const float* __restrict__ whh,
        const float* __restrict__ w1, const float* __restrict__ w2,
        u16* __restrict__ wkvb, u16* __restrict__ wqb, u16* __restrict__ wihb,
        u16* __restrict__ whhb, u16* __restrict__ w1b, u16* __restrict__ w2b) {
    int i = blockIdx.x * 256 + threadIdx.x;
    if (i < 131072) { wkvb[i] = f2bf(i < 65536 ? wk[i] : wv[i - 65536]); return; }
    i -= 131072;
    if (i < 65536) { wqb[i] = f2bf(wq[i]); return; }
    i -= 65536;
    if (i < 196608) { wihb[i] = f2bf(wih[i]); return; }
    i -= 196608;
    if (i < 196608) { whhb[i] = f2bf(whh[i]); return; }
    i -= 196608;
    if (i < 65536) { w1b[i] = f2bf(w1[i]); return; }
    i -= 65536;
    w2b[i] = f2bf(w2[i]);
}

// ---------------- fused LN + K/V projection GEMM ----------------------------
// block = 64 input rows x 512 out cols. LN(inputs) computed in-register,
// staged once to LDS; W fragments loaded direct from global (L2-resident).
// Per-wave epilogue buffers -> single __syncthreads in the whole kernel.
__global__ __launch_bounds__(256) void ln_gemm_kv(
        const float* __restrict__ inp, const float* __restrict__ g,
        const float* __restrict__ bt, const u16* __restrict__ W,
        const float* __restrict__ bk, const float* __restrict__ bv,
        u16* __restrict__ kout, u16* __restrict__ vT) {
    __shared__ u16 A_lds[64*264];       // 33792 B
    __shared__ u16 ctw[4][64*36];       // 18432 B (per-wave epilogue buffers)
    const int blk = blockIdx.x;
    const long r0 = (long)blk * 64;
    const int tid = threadIdx.x, wid = tid >> 6, lane = tid & 63;
    const int l15 = lane & 15, quad = lane >> 4, kq = quad * 8;

    // LN: 16 rows per wave, shuffle-reduce over the 64-lane row
#pragma unroll 4
    for (int i = 0; i < 16; i++) {
        int row = wid*16 + i;
        float4 v = reinterpret_cast<const float4*>(inp + (r0 + row)*256)[lane];
        float s = v.x + v.y + v.z + v.w;
        float ss = v.x*v.x + v.y*v.y + v.z*v.z + v.w*v.w;
#pragma unroll
        for (int off = 32; off >= 1; off >>= 1) { s += __shfl_xor(s, off, 64); ss += __shfl_xor(ss, off, 64); }
        float mean = s * (1.0f/256.0f);
        float rstd = rsqrtf(ss * (1.0f/256.0f) - mean*mean + 1e-5f);
        float4 g4 = reinterpret_cast<const float4*>(g)[lane];
        float4 b4 = reinterpret_cast<const float4*>(bt)[lane];
        ushort4 o;
        o.x = f2bf((v.x-mean)*rstd*g4.x + b4.x);
        o.y = f2bf((v.y-mean)*rstd*g4.y + b4.y);
        o.z = f2bf((v.z-mean)*rstd*g4.z + b4.z);
        o.w = f2bf((v.w-mean)*rstd*g4.w + b4.w);
        *reinterpret_cast<ushort4*>(&A_lds[row*264 + lane*4]) = o;
    }
    __syncthreads();

    const long bb = r0 >> 12;
    const long nb0 = r0 & 4095;
    for (int ct = 0; ct < 4; ct++) {
        const int o0 = ct * 128;
        f32x4 acc[4][2];
#pragma unroll
        for (int rt = 0; rt < 4; rt++) { acc[rt][0] = (f32x4){0.f,0.f,0.f,0.f}; acc[rt][1] = (f32x4){0.f,0.f,0.f,0.f}; }
        const u16* Wb0 = &W[(size_t)(o0 + wid*32 + l15)*256 + kq];
        const u16* Wb1 = Wb0 + 16*256;
#pragma unroll
        for (int kk = 0; kk < 8; kk++) {
            short8 wf0 = *reinterpret_cast<const short8*>(&Wb0[kk*32]);
            short8 wf1 = *reinterpret_cast<const short8*>(&Wb1[kk*32]);
#pragma unroll
            for (int rt = 0; rt < 4; rt++) {
                short8 af = *reinterpret_cast<const short8*>(&A_lds[(rt*16 + l15)*264 + kk*32 + kq]);
                acc[rt][0] = mfma16(af, wf0, acc[rt][0]);
                acc[rt][1] = mfma16(af, wf1, acc[rt][1]);
            }
        }
        if (ct < 2) {
            // k half: per-wave transpose buffer [64][36], then 64B-chunk stores
            float bb0 = bk[o0 + wid*32 + l15], bb1 = bk[o0 + wid*32 + 16 + l15];
            u16* C = ctw[wid];
#pragma unroll
            for (int rt = 0; rt < 4; rt++) {
                int m = rt*16 + quad*4;
#pragma unroll
                for (int r = 0; r < 4; r++) {
                    C[(m+r)*36 + l15]      = f2bf(acc[rt][0][r] + bb0);
                    C[(m+r)*36 + 16 + l15] = f2bf(acc[rt][1][r] + bb1);
                }
            }
#pragma unroll
            for (int it = 0; it < 4; it++) {
                int m = it*16 + (lane >> 2);
                short8 val = *reinterpret_cast<const short8*>(&C[m*36 + (lane & 3)*8]);
                *reinterpret_cast<short8*>(&kout[(r0 + m)*256 + o0 + wid*32 + (lane & 3)*8]) = val;
            }
        } else {
            // v half: transposed to vT[b][d][n]; per-wave [32][72] buffer
            float bb0 = bv[(o0-256) + wid*32 + l15], bb1 = bv[(o0-256) + wid*32 + 16 + l15];
            u16* C = ctw[wid];
#pragma unroll
            for (int rt = 0; rt < 4; rt++) {
                int m = rt*16 + quad*4;
                ushort4 p0, p1;
                p0.x = f2bf(acc[rt][0][0] + bb0); p0.y = f2bf(acc[rt][0][1] + bb0);
                p0.z = f2bf(acc[rt][0][2] + bb0); p0.w = f2bf(acc[rt][0][3] + bb0);
                p1.x = f2bf(acc[rt][1][0] + bb1); p1.y = f2bf(acc[rt][1][1] + bb1);
                p1.z = f2bf(acc[rt][1][2] + bb1); p1.w = f2bf(acc[rt][1][3] + bb1);
                *reinterpret_cast<ushort4*>(&C[(l15)*72 + m])      = p0;
                *reinterpret_cast<ushort4*>(&C[(16 + l15)*72 + m]) = p1;
            }
#pragma unroll
            for (int it = 0; it < 4; it++) {
                int lc = it*8 + (lane >> 3);
                short8 val = *reinterpret_cast<const short8*>(&C[lc*72 + (lane & 7)*8]);
                long d = (o0 - 256) + wid*32 + lc;
                *reinterpret_cast<short8*>(&vT[(bb*256 + d)*4096 + nb0 + (lane & 7)*8]) = val;
            }
        }
        // ctw is per-wave and DS ops are in-order per wave: no barrier needed
    }
}

// ---------------- q projection (iteration 0 only) ---------------------------
__global__ __launch_bounds__(256) void q_proj(
        const float* __restrict__ slots, const u16* __restrict__ wqb,
        const float* __restrict__ bq, const float* __restrict__ gs, const float* __restrict__ bs,
        u16* __restrict__ qb) {
    __shared__ u16 sn[16*264];
    const int b = blockIdx.x;
    const int tid = threadIdx.x, wid = tid >> 6, lane = tid & 63;
    const int l15 = lane & 15, kq = (lane >> 4) * 8;
    for (int rr = wid; rr < 8; rr += 4) {
        float4 v = reinterpret_cast<const float4*>(slots + (size_t)(b*8 + rr)*256)[lane];
        float s = v.x + v.y + v.z + v.w;
        float ss = v.x*v.x + v.y*v.y + v.z*v.z + v.w*v.w;
#pragma unroll
        for (int off = 32; off >= 1; off >>= 1) { s += __shfl_xor(s, off, 64); ss += __shfl_xor(ss, off, 64); }
        float mean = s * (1.f/256.f);
        float rstd = rsqrtf(ss * (1.f/256.f) - mean*mean + 1e-5f);
        float4 g4 = reinterpret_cast<const float4*>(gs)[lane];
        float4 b4 = reinterpret_cast<const float4*>(bs)[lane];
        ushort4 o;
        o.x = f2bf((v.x-mean)*rstd*g4.x + b4.x);
        o.y = f2bf((v.y-mean)*rstd*g4.y + b4.y);
        o.z = f2bf((v.z-mean)*rstd*g4.z + b4.z);
        o.w = f2bf((v.w-mean)*rstd*g4.w + b4.w);
        *reinterpret_cast<ushort4*>(&sn[rr*264 + lane*4]) = o;
    }
    {
        ushort4 z = {0,0,0,0};
        for (int rr = 8 + wid; rr < 16; rr += 4)
            *reinterpret_cast<ushort4*>(&sn[rr*264 + lane*4]) = z;
    }
    __syncthreads();
    short8 af[8];
#pragma unroll
    for (int k = 0; k < 8; k++) af[k] = *reinterpret_cast<const short8*>(&sn[l15*264 + k*32 + kq]);
#pragma unroll
    for (int ct = 0; ct < 4; ct++) {
        int o0 = (wid*4 + ct)*16;
        f32x4 a = (f32x4){0.f,0.f,0.f,0.f};
#pragma unroll
        for (int k = 0; k < 8; k++) {
            short8 bw = *reinterpret_cast<const short8*>(&wqb[(size_t)(o0 + l15)*256 + k*32 + kq]);
            a = mfma16(af[k], bw, a);
        }
        if (lane < 32) {
            int sb = (lane >> 4)*4;
            float bb = bq[o0 + l15];
#pragma unroll
            for (int r = 0; r < 4; r++)
                qb[(size_t)(b*8 + sb + r)*256 + o0 + l15] = f2bf(a[r] + bb);
        }
    }
}

// ---------------- fused attention pass: barrier-free per-wave streams -------
// 512 blocks; wave owns a 128-n strip: dots (full 8x64 per 64-n round) ->
// softmax -> P via per-wave LDS transpose -> PV over all 256 d.
__global__ __launch_bounds__(256) void attn(
        const u16* __restrict__ qb, const u16* __restrict__ kb,
        const u16* __restrict__ vT, float* __restrict__ num, float* __restrict__ den) {
    __shared__ u16 pb_all[4][16*72];
    const int b = blockIdx.x >> 3;
    const int nseg = (blockIdx.x & 7) * 512;
    const int tid = threadIdx.x, wid = tid >> 6, lane = tid & 63;
    const int l15 = lane & 15, quad = lane >> 4, kq = quad * 8;
    u16* pb = pb_all[wid];
    {   // zero P pad rows 8..15 of own wave's buffer (cols 0..63 are read)
        short8 z = {0,0,0,0,0,0,0,0};
        int r8 = 8 + (lane >> 3), c8 = (lane & 7)*8;
        *reinterpret_cast<short8*>(&pb[r8*72 + c8]) = z;
    }
    // q A-fragment direct from global, rows >=8 zeroed (clamped row: no OOB)
    short8 aq[8];
    {
        const u16* qrow = &qb[((size_t)b*8 + (l15 & 7))*256 + kq];
        short8 z = {0,0,0,0,0,0,0,0};
#pragma unroll
        for (int kk = 0; kk < 8; kk++) {
            short8 t = *reinterpret_cast<const short8*>(&qrow[kk*32]);
            aq[kk] = (l15 < 8) ? t : z;
        }
    }
    const int n_w = nseg + wid*128;
    const u16* kbase = &kb[((size_t)b*4096 + n_w + l15)*256 + kq];
    const u16* vbase = &vT[((size_t)b*256 + l15)*4096 + n_w + kq];
    f32x4 acc[16];
#pragma unroll
    for (int dt = 0; dt < 16; dt++) acc[dt] = (f32x4){0.f,0.f,0.f,0.f};
    float psum[4] = {0.f,0.f,0.f,0.f};
    short8 kf[8];
#pragma unroll
    for (int kk = 0; kk < 8; kk++) kf[kk] = *reinterpret_cast<const short8*>(&kbase[kk*32]);

    for (int rnd = 0; rnd < 2; rnd++) {
        const int nro = rnd*64;
        f32x4 dots[4];
#pragma unroll
        for (int nt = 0; nt < 4; nt++) {
            short8 kn[8];
            const int next = rnd*4 + nt + 1;
            if (next < 8) {
                const u16* kp = kbase + (size_t)(next*16)*256;
#pragma unroll
                for (int kk = 0; kk < 8; kk++) kn[kk] = *reinterpret_cast<const short8*>(&kp[kk*32]);
            }
            f32x4 d = (f32x4){0.f,0.f,0.f,0.f};
#pragma unroll
            for (int kk = 0; kk < 8; kk++) d = mfma16(aq[kk], kf[kk], d);
            dots[nt] = d;
            if (next < 8) {
#pragma unroll
                for (int kk = 0; kk < 8; kk++) kf[kk] = kn[kk];
            }
        }
        // early-issue first v pair for this round (independent of P)
        const u16* vr = vbase + nro;
        short8 v0 = *reinterpret_cast<const short8*>(vr);
        short8 v1 = *reinterpret_cast<const short8*>(vr + 32);
        // softmax over slots per column + write P (C-layout) to own LDS buf
#pragma unroll
        for (int nt = 0; nt < 4; nt++) {
            float t0 = dots[nt][0]*0.0625f, t1 = dots[nt][1]*0.0625f;
            float t2 = dots[nt][2]*0.0625f, t3 = dots[nt][3]*0.0625f;
            float m4 = fmaxf(fmaxf(t0,t1), fmaxf(t2,t3));
            float m8 = fmaxf(m4, __shfl_xor(m4, 16, 64));
            float e0 = __expf(t0-m8), e1 = __expf(t1-m8), e2 = __expf(t2-m8), e3 = __expf(t3-m8);
            float s4 = e0+e1+e2+e3;
            float s8 = s4 + __shfl_xor(s4, 16, 64);
            float inv = 1.0f / s8;
            u16 h0 = f2bf(e0*inv + 1e-8f);
            u16 h1 = f2bf(e1*inv + 1e-8f);
            u16 h2 = f2bf(e2*inv + 1e-8f);
            u16 h3 = f2bf(e3*inv + 1e-8f);
            if (lane < 32) {
                int sb = quad*4, col = nt*16 + l15;
                pb[(sb+0)*72 + col] = h0;
                pb[(sb+1)*72 + col] = h1;
                pb[(sb+2)*72 + col] = h2;
                pb[(sb+3)*72 + col] = h3;
                psum[0] += bf2f(h0); psum[1] += bf2f(h1);
                psum[2] += bf2f(h2); psum[3] += bf2f(h3);
            }
        }
        __builtin_amdgcn_s_waitcnt(0xC07F);   // lgkmcnt(0): p-writes drained (same-wave)
        short8 ap0 = *reinterpret_cast<const short8*>(&pb[l15*72 + kq]);
        short8 ap1 = *reinterpret_cast<const short8*>(&pb[l15*72 + 32 + kq]);
        // PV over 16 d-tiles, depth-1 v prefetch
#pragma unroll
        for (int dt = 0; dt < 16; dt++) {
            short8 nv0, nv1;
            if (dt < 15) {
                const u16* vn = vr + (size_t)((dt+1)*16)*4096;
                nv0 = *reinterpret_cast<const short8*>(vn);
                nv1 = *reinterpret_cast<const short8*>(vn + 32);
            }
            acc[dt] = mfma16(ap0, v0, acc[dt]);
            acc[dt] = mfma16(ap1, v1, acc[dt]);
            if (dt < 15) { v0 = nv0; v1 = nv1; }
        }
    }
#pragma unroll
    for (int off = 1; off < 16; off <<= 1) {
#pragma unroll
        for (int r = 0; r < 4; r++) psum[r] += __shfl_xor(psum[r], off, 64);
    }
    if (lane < 32) {
        int sb = quad*4;
        if (l15 == 0) {
#pragma unroll
            for (int r = 0; r < 4; r++) atomicAdd(&den[b*8 + sb + r], psum[r]);
        }
#pragma unroll
        for (int dt = 0; dt < 16; dt++) {
            int d0 = dt*16 + l15;
#pragma unroll
            for (int r = 0; r < 4; r++)
                atomicAdd(&num[((size_t)b*8 + sb + r)*256 + d0], acc[dt][r]);
        }
    }
}

// ---------------- per-iteration tail: updates -> GRU -> MLP -> slots (+q) ---
__global__ __launch_bounds__(768) void finalize(
        const float* __restrict__ slots_in, const float* __restrict__ num, const float* __restrict__ den,
        const u16* __restrict__ wihb, const float* __restrict__ bih,
        const u16* __restrict__ whhb, const float* __restrict__ bhh,
        const u16* __restrict__ w1b, const float* __restrict__ b1v,
        const u16* __restrict__ w2b, const float* __restrict__ b2v,
        const float* __restrict__ gff, const float* __restrict__ bff,
        float* __restrict__ slots_out,
        const u16* __restrict__ wqb, const float* __restrict__ bq,
        const float* __restrict__ gs, const float* __restrict__ bs,
        u16* __restrict__ qb, int do_q) {
    __shared__ u16 updb[16*264];
    __shared__ u16 prevb[16*264];
    __shared__ u16 lnb[16*264];
    __shared__ float gx[8*776];
    __shared__ float gh[8*776];
    __shared__ float snew[8*256];
    float* sfin = gx;    // reuse after gates consumed
    const int b = blockIdx.x;
    const int tid = threadIdx.x, wid = tid >> 6, lane = tid & 63;
    const int l15 = lane & 15, kq = (lane >> 4) * 8;
    for (int idx = tid; idx < 2048; idx += 768) {
        int s = idx >> 8, d = idx & 255;
        updb[s*264 + d] = f2bf(num[(size_t)(b*8 + s)*256 + d] / den[b*8 + s]);
        prevb[s*264 + d] = f2bf(slots_in[(size_t)(b*8 + s)*256 + d]);
        updb[(8+s)*264 + d] = 0;
        prevb[(8+s)*264 + d] = 0;
    }
    __syncthreads();
    short8 au[8], ap[8];
#pragma unroll
    for (int k = 0; k < 8; k++) {
        au[k] = *reinterpret_cast<const short8*>(&updb[l15*264 + k*32 + kq]);
        ap[k] = *reinterpret_cast<const short8*>(&prevb[l15*264 + k*32 + kq]);
    }
#pragma unroll
    for (int ct = 0; ct < 4; ct++) {
        int o0 = (wid*4 + ct)*16;
        f32x4 ax = (f32x4){0.f,0.f,0.f,0.f}, ah = (f32x4){0.f,0.f,0.f,0.f};
#pragma unroll
        for (int k = 0; k < 8; k++) {
            short8 bx = *reinterpret_cast<const short8*>(&wihb[(size_t)(o0 + l15)*256 + k*32 + kq]);
            short8 bh = *reinterpret_cast<const short8*>(&whhb[(size_t)(o0 + l15)*256 + k*32 + kq]);
            ax = mfma16(au[k], bx, ax);
            ah = mfma16(ap[k], bh, ah);
        }
        if (lane < 32) {
            int sb = (lane >> 4)*4, o = o0 + l15;
            float bxs = bih[o], bhs = bhh[o];
#pragma unroll
            for (int r = 0; r < 4; r++) {
                gx[(sb+r)*776 + o] = ax[r] + bxs;
                gh[(sb+r)*776 + o] = ah[r] + bhs;
            }
        }
    }
    __syncthreads();
    for (int idx = tid; idx < 2048; idx += 768) {
        int s = idx >> 8, j = idx & 255;
        float xr = gx[s*776 + j], xz = gx[s*776 + 256 + j], xn = gx[s*776 + 512 + j];
        float hr = gh[s*776 + j], hz = gh[s*776 + 256 + j], hn = gh[s*776 + 512 + j];
        float r_ = 1.f/(1.f + __expf(-(xr+hr)));
        float z_ = 1.f/(1.f + __expf(-(xz+hz)));
        float n_ = tanhf(xn + r_*hn);
        float pv = slots_in[(size_t)(b*8 + s)*256 + j];
        snew[s*256 + j] = (1.f - z_)*n_ + z_*pv;
    }
    __syncthreads();
    if (wid < 8) {
        int rr = wid;
        float4 v = reinterpret_cast<const float4*>(&snew[rr*256])[lane];
        float s = v.x + v.y + v.z + v.w;
        float ss = v.x*v.x + v.y*v.y + v.z*v.z + v.w*v.w;
#pragma unroll
        for (int off = 32; off >= 1; off >>= 1) { s += __shfl_xor(s, off, 64); ss += __shfl_xor(ss, off, 64); }
        float mean = s * (1.f/256.f);
        float rstd = rsqrtf(ss * (1.f/256.f) - mean*mean + 1e-5f);
        float4 g4 = reinterpret_cast<const float4*>(gff)[lane];
        float4 b4 = reinterpret_cast<const float4*>(bff)[lane];
        ushort4 o;
        o.x = f2bf((v.x-mean)*rstd*g4.x + b4.x);
        o.y = f2bf((v.y-mean)*rstd*g4.y + b4.y);
        o.z = f2bf((v.z-mean)*rstd*g4.z + b4.z);
        o.w = f2bf((v.w-mean)*rstd*g4.w + b4.w);
        *reinterpret_cast<ushort4*>(&lnb[rr*264 + lane*4]) = o;
    } else {
        ushort4 z = {0,0,0,0};
        *reinterpret_cast<ushort4*>(&lnb[wid*264 + lane*4]) = z;
        *reinterpret_cast<ushort4*>(&lnb[(wid+4)*264 + lane*4]) = z;
    }
    __syncthreads();
    short8 al[8];
#pragma unroll
    for (int k = 0; k < 8; k++) al[k] = *reinterpret_cast<const short8*>(&lnb[l15*264 + k*32 + kq]);
    for (int ct = wid; ct < 16; ct += 12) {
        int o0 = ct*16;
        f32x4 a = (f32x4){0.f,0.f,0.f,0.f};
#pragma unroll
        for (int k = 0; k < 8; k++) {
            short8 bw = *reinterpret_cast<const short8*>(&w1b[(size_t)(o0 + l15)*256 + k*32 + kq]);
            a = mfma16(al[k], bw, a);
        }
        if (lane < 32) {
            int sb = (lane >> 4)*4, o = o0 + l15;
            float bb = b1v[o];
#pragma unroll
            for (int r = 0; r < 4; r++)
                updb[(sb+r)*264 + o] = f2bf(fmaxf(a[r] + bb, 0.f));
        }
    }
    __syncthreads();
    short8 ah2[8];
#pragma unroll
    for (int k = 0; k < 8; k++) ah2[k] = *reinterpret_cast<const short8*>(&updb[l15*264 + k*32 + kq]);
    for (int ct = wid; ct < 16; ct += 12) {
        int o0 = ct*16;
        f32x4 a = (f32x4){0.f,0.f,0.f,0.f};
#pragma unroll
        for (int k = 0; k < 8; k++) {
            short8 bw = *reinterpret_cast<const short8*>(&w2b[(size_t)(o0 + l15)*256 + k*32 + kq]);
            a = mfma16(ah2[k], bw, a);
        }
        if (lane < 32) {
            int sb = (lane >> 4)*4, o = o0 + l15;
            float bb = b2v[o];
#pragma unroll
            for (int r = 0; r < 4; r++) {
                float vfin = snew[(sb+r)*256 + o] + a[r] + bb;
                slots_out[(size_t)(b*8 + sb + r)*256 + o] = vfin;
                sfin[(sb+r)*256 + o] = vfin;
            }
        }
    }
    if (!do_q) return;
    __syncthreads();
    // fused q projection for next iteration: q = LN(slots_new)@wq^T + bq
    if (wid < 8) {
        int rr = wid;
        float4 v = reinterpret_cast<const float4*>(&sfin[rr*256])[lane];
        float s = v.x + v.y + v.z + v.w;
        float ss = v.x*v.x + v.y*v.y + v.z*v.z + v.w*v.w;
#pragma unroll
        for (int off = 32; off >= 1; off >>= 1) { s += __shfl_xor(s, off, 64); ss += __shfl_xor(ss, off, 64); }
        float mean = s * (1.f/256.f);
        float rstd = rsqrtf(ss * (1.f/256.f) - mean*mean + 1e-5f);
        float4 g4 = reinterpret_cast<const float4*>(gs)[lane];
        float4 b4 = reinterpret_cast<const float4*>(bs)[lane];
        ushort4 o;
        o.x = f2bf((v.x-mean)*rstd*g4.x + b4.x);
        o.y = f2bf((v.y-mean)*rstd*g4.y + b4.y);
        o.z = f2bf((v.z-mean)*rstd*g4.z + b4.z);
        o.w = f2bf((v.w-mean)*rstd*g4.w + b4.w);
        *reinterpret_cast<ushort4*>(&lnb[rr*264 + lane*4]) = o;
    } else {
        ushort4 z = {0,0,0,0};
        *reinterpret_cast<ushort4*>(&lnb[wid*264 + lane*4]) = z;
        *reinterpret_cast<ushort4*>(&lnb[(wid+4)*264 + lane*4]) = z;
    }
    __syncthreads();
    short8 alq[8];
#pragma unroll
    for (int k = 0; k < 8; k++) alq[k] = *reinterpret_cast<const short8*>(&lnb[l15*264 + k*32 + kq]);
    for (int ct = wid; ct < 16; ct += 12) {
        int o0 = ct*16;
        f32x4 a = (f32x4){0.f,0.f,0.f,0.f};
#pragma unroll
        for (int k = 0; k < 8; k++) {
            short8 bw = *reinterpret_cast<const short8*>(&wqb[(size_t)(o0 + l15)*256 + k*32 + kq]);
            a = mfma16(alq[k], bw, a);
        }
        if (lane < 32) {
            int sb = (lane >> 4)*4, o = o0 + l15;
            float bb = bq[o];
#pragma unroll
            for (int r = 0; r < 4; r++)
                qb[(size_t)(b*8 + sb + r)*256 + o] = f2bf(a[r] + bb);
        }
    }
}

extern "C" void kernel_launch(void* const* d_in, const int* in_sizes, int n_in,
                              void* d_out, int out_size, void* d_ws, size_t ws_size,
                              hipStream_t stream) {
    (void)in_sizes; (void)n_in; (void)out_size;
    const float* inputs     = (const float*)d_in[0];
    const float* init_slots = (const float*)d_in[1];
    const float* wq  = (const float*)d_in[2];
    const float* bq  = (const float*)d_in[3];
    const float* wk  = (const float*)d_in[4];
    const float* bk  = (const float*)d_in[5];
    const float* wv  = (const float*)d_in[6];
    const float* bv  = (const float*)d_in[7];
    const float* wih = (const float*)d_in[8];
    const float* bih = (const float*)d_in[9];
    const float* whh = (const float*)d_in[10];
    const float* bhh = (const float*)d_in[11];
    const float* w1  = (const float*)d_in[12];
    const float* b1  = (const float*)d_in[13];
    const float* w2  = (const float*)d_in[14];
    const float* b2  = (const float*)d_in[15];
    const float* g_in = (const float*)d_in[16];
    const float* b_in = (const float*)d_in[17];
    const float* g_sl = (const float*)d_in[18];
    const float* b_sl = (const float*)d_in[19];
    const float* g_ff = (const float*)d_in[20];
    const float* b_ff = (const float*)d_in[21];

    char* ws = (char*)d_ws;
    size_t off = 0;
    auto alloc = [&](size_t bytes) -> void* {
        void* p = ws + off;
        off += (bytes + 255) & ~(size_t)255;
        return p;
    };
    u16* kbf   = (u16*)alloc((size_t)GROWS * ND * 2);   // k bf16 [b][n][d]
    u16* vTb   = (u16*)alloc((size_t)GROWS * ND * 2);   // v bf16 transposed [b][d][n]
    u16* qbf   = (u16*)alloc((size_t)NB * NS * ND * 2);
    float* slots = (float*)alloc((size_t)NB * NS * ND * 4);
    float* numb  = (float*)alloc((size_t)NB * NS * ND * 4);  // + den contiguous
    float* denb  = (float*)alloc((size_t)NB * NS * 4);
    u16* wkvb = (u16*)alloc(131072 * 2);
    u16* wqb  = (u16*)alloc(65536 * 2);
    u16* wihb = (u16*)alloc(196608 * 2);
    u16* whhb = (u16*)alloc(196608 * 2);
    u16* w1b  = (u16*)alloc(65536 * 2);
    u16* w2b  = (u16*)alloc(65536 * 2);
    if (off > ws_size) return;  // insufficient workspace -> visible failure

    prep_w<<<2816, 256, 0, stream>>>(wk, wv, wq, wih, whh, w1, w2,
                                     wkvb, wqb, wihb, whhb, w1b, w2b);
    hipMemcpyAsync(slots, init_slots, (size_t)NB * NS * ND * 4,
                   hipMemcpyDeviceToDevice, stream);
    ln_gemm_kv<<<GROWS / 64, 256, 0, stream>>>(inputs, g_in, b_in, wkvb, bk, bv, kbf, vTb);
    q_proj<<<NB, 256, 0, stream>>>(slots, wqb, bq, g_sl, b_sl, qbf);
    for (int it = 0; it < 3; it++) {
        hipMemsetAsync(numb, 0, (size_t)(NB*NS*ND + NB*NS) * 4, stream);
        attn<<<NB * 8, 256, 0, stream>>>(qbf, kbf, vTb, numb, denb);
        float* outp = (it == 2) ? (float*)d_out : slots;
        finalize<<<NB, 768, 0, stream>>>(slots, numb, denb, wihb, bih, whhb, bhh,
                                         w1b, b1, w2b, b2, g_ff, b_ff, outp,
                                         wqb, bq, g_sl, b_sl, qbf, (it < 2) ? 1 : 0);
    }
}

// Round 5
// 903.378 us; speedup vs baseline: 1.0513x; 1.0513x over previous
//
#include <hip/hip_runtime.h>
#include <hip/hip_bf16.h>
#include <stdint.h>

typedef unsigned short u16;
typedef __attribute__((ext_vector_type(8))) short short8;
typedef __attribute__((ext_vector_type(4))) float f32x4;

#define NB 64
#define NN 4096
#define NS 8
#define ND 256
#define GROWS (NB*NN)   // 262144

__device__ inline u16 f2bf(float f) {
    uint32_t u = __float_as_uint(f);
    u = (u + 0x7FFFu + ((u >> 16) & 1u)) >> 16;
    return (u16)u;
}
__device__ inline float bf2f(u16 h) {
    return __uint_as_float(((uint32_t)h) << 16);
}
__device__ inline f32x4 mfma16(short8 a, short8 b, f32x4 c) {
    return __builtin_amdgcn_mfma_f32_16x16x32_bf16(a, b, c, 0, 0, 0);
}

// ---------------- weight conversion fp32 -> bf16 (once per launch) ----------
__global__ __launch_bounds__(256) void prep_w(
        const float* __restrict__ wk, const float* __restrict__ wv, const float* __restrict__ wq,
        const float* __restrict__ wih, const float* __restrict__ whh,
        const float* __restrict__ w1, const float* __restrict__ w2,
        u16* __restrict__ wkvb, u16* __restrict__ wqb, u16* __restrict__ wihb,
        u16* __restrict__ whhb, u16* __restrict__ w1b, u16* __restrict__ w2b) {
    int i = blockIdx.x * 256 + threadIdx.x;
    if (i < 131072) { wkvb[i] = f2bf(i < 65536 ? wk[i] : wv[i - 65536]); return; }
    i -= 131072;
    if (i < 65536) { wqb[i] = f2bf(wq[i]); return; }
    i -= 65536;
    if (i < 196608) { wihb[i] = f2bf(wih[i]); return; }
    i -= 196608;
    if (i < 196608) { whhb[i] = f2bf(whh[i]); return; }
    i -= 196608;
    if (i < 65536) { w1b[i] = f2bf(w1[i]); return; }
    i -= 65536;
    w2b[i] = f2bf(w2[i]);
}

// ---------------- fused LN + K/V projection GEMM ----------------------------
// block = 64 input rows x 512 out cols. LN(inputs) in-register -> LDS once;
// all 16 W fragments of a ct preloaded to registers before the MFMA loop.
__global__ __launch_bounds__(256) void ln_gemm_kv(
        const float* __restrict__ inp, const float* __restrict__ g,
        const float* __restrict__ bt, const u16* __restrict__ W,
        const float* __restrict__ bk, const float* __restrict__ bv,
        u16* __restrict__ kout, u16* __restrict__ vT) {
    __shared__ u16 A_lds[64*264];       // 33792 B
    __shared__ u16 ctw[4][64*36];       // 18432 B (per-wave epilogue buffers)
    const int blk = blockIdx.x;
    const long r0 = (long)blk * 64;
    const int tid = threadIdx.x, wid = tid >> 6, lane = tid & 63;
    const int l15 = lane & 15, quad = lane >> 4, kq = quad * 8;

    // LN: 16 rows per wave; g/b hoisted out of the loop
    {
        float4 g4 = reinterpret_cast<const float4*>(g)[lane];
        float4 b4 = reinterpret_cast<const float4*>(bt)[lane];
#pragma unroll 4
        for (int i = 0; i < 16; i++) {
            int row = wid*16 + i;
            float4 v = reinterpret_cast<const float4*>(inp + (r0 + row)*256)[lane];
            float s = v.x + v.y + v.z + v.w;
            float ss = v.x*v.x + v.y*v.y + v.z*v.z + v.w*v.w;
#pragma unroll
            for (int off = 32; off >= 1; off >>= 1) { s += __shfl_xor(s, off, 64); ss += __shfl_xor(ss, off, 64); }
            float mean = s * (1.0f/256.0f);
            float rstd = rsqrtf(ss * (1.0f/256.0f) - mean*mean + 1e-5f);
            ushort4 o;
            o.x = f2bf((v.x-mean)*rstd*g4.x + b4.x);
            o.y = f2bf((v.y-mean)*rstd*g4.y + b4.y);
            o.z = f2bf((v.z-mean)*rstd*g4.z + b4.z);
            o.w = f2bf((v.w-mean)*rstd*g4.w + b4.w);
            *reinterpret_cast<ushort4*>(&A_lds[row*264 + lane*4]) = o;
        }
    }
    __syncthreads();

    const long bb = r0 >> 12;
    const long nb0 = r0 & 4095;
    for (int ct = 0; ct < 4; ct++) {
        const int o0 = ct * 128;
        f32x4 acc[4][2];
#pragma unroll
        for (int rt = 0; rt < 4; rt++) { acc[rt][0] = (f32x4){0.f,0.f,0.f,0.f}; acc[rt][1] = (f32x4){0.f,0.f,0.f,0.f}; }
        // preload ALL W fragments for this ct (16 independent global loads)
        const u16* Wb0 = &W[(size_t)(o0 + wid*32 + l15)*256 + kq];
        const u16* Wb1 = Wb0 + 16*256;
        short8 wf0[8], wf1[8];
#pragma unroll
        for (int kk = 0; kk < 8; kk++) {
            wf0[kk] = *reinterpret_cast<const short8*>(&Wb0[kk*32]);
            wf1[kk] = *reinterpret_cast<const short8*>(&Wb1[kk*32]);
        }
#pragma unroll
        for (int kk = 0; kk < 8; kk++) {
#pragma unroll
            for (int rt = 0; rt < 4; rt++) {
                short8 af = *reinterpret_cast<const short8*>(&A_lds[(rt*16 + l15)*264 + kk*32 + kq]);
                acc[rt][0] = mfma16(af, wf0[kk], acc[rt][0]);
                acc[rt][1] = mfma16(af, wf1[kk], acc[rt][1]);
            }
        }
        if (ct < 2) {
            // k half: per-wave transpose buffer [64][36], then 64B-chunk stores
            float bb0 = bk[o0 + wid*32 + l15], bb1 = bk[o0 + wid*32 + 16 + l15];
            u16* C = ctw[wid];
#pragma unroll
            for (int rt = 0; rt < 4; rt++) {
                int m = rt*16 + quad*4;
#pragma unroll
                for (int r = 0; r < 4; r++) {
                    C[(m+r)*36 + l15]      = f2bf(acc[rt][0][r] + bb0);
                    C[(m+r)*36 + 16 + l15] = f2bf(acc[rt][1][r] + bb1);
                }
            }
#pragma unroll
            for (int it = 0; it < 4; it++) {
                int m = it*16 + (lane >> 2);
                short8 val = *reinterpret_cast<const short8*>(&C[m*36 + (lane & 3)*8]);
                *reinterpret_cast<short8*>(&kout[(r0 + m)*256 + o0 + wid*32 + (lane & 3)*8]) = val;
            }
        } else {
            // v half: transposed to vT[b][d][n]; per-wave [32][72] buffer
            float bb0 = bv[(o0-256) + wid*32 + l15], bb1 = bv[(o0-256) + wid*32 + 16 + l15];
            u16* C = ctw[wid];
#pragma unroll
            for (int rt = 0; rt < 4; rt++) {
                int m = rt*16 + quad*4;
                ushort4 p0, p1;
                p0.x = f2bf(acc[rt][0][0] + bb0); p0.y = f2bf(acc[rt][0][1] + bb0);
                p0.z = f2bf(acc[rt][0][2] + bb0); p0.w = f2bf(acc[rt][0][3] + bb0);
                p1.x = f2bf(acc[rt][1][0] + bb1); p1.y = f2bf(acc[rt][1][1] + bb1);
                p1.z = f2bf(acc[rt][1][2] + bb1); p1.w = f2bf(acc[rt][1][3] + bb1);
                *reinterpret_cast<ushort4*>(&C[(l15)*72 + m])      = p0;
                *reinterpret_cast<ushort4*>(&C[(16 + l15)*72 + m]) = p1;
            }
#pragma unroll
            for (int it = 0; it < 4; it++) {
                int lc = it*8 + (lane >> 3);
                short8 val = *reinterpret_cast<const short8*>(&C[lc*72 + (lane & 7)*8]);
                long d = (o0 - 256) + wid*32 + lc;
                *reinterpret_cast<short8*>(&vT[(bb*256 + d)*4096 + nb0 + (lane & 7)*8]) = val;
            }
        }
        // ctw is per-wave and DS ops are in-order per wave: no barrier needed
    }
}

// ---------------- q projection (iteration 0 only) ---------------------------
__global__ __launch_bounds__(256) void q_proj(
        const float* __restrict__ slots, const u16* __restrict__ wqb,
        const float* __restrict__ bq, const float* __restrict__ gs, const float* __restrict__ bs,
        u16* __restrict__ qb) {
    __shared__ u16 sn[16*264];
    const int b = blockIdx.x;
    const int tid = threadIdx.x, wid = tid >> 6, lane = tid & 63;
    const int l15 = lane & 15, kq = (lane >> 4) * 8;
    for (int rr = wid; rr < 8; rr += 4) {
        float4 v = reinterpret_cast<const float4*>(slots + (size_t)(b*8 + rr)*256)[lane];
        float s = v.x + v.y + v.z + v.w;
        float ss = v.x*v.x + v.y*v.y + v.z*v.z + v.w*v.w;
#pragma unroll
        for (int off = 32; off >= 1; off >>= 1) { s += __shfl_xor(s, off, 64); ss += __shfl_xor(ss, off, 64); }
        float mean = s * (1.f/256.f);
        float rstd = rsqrtf(ss * (1.f/256.f) - mean*mean + 1e-5f);
        float4 g4 = reinterpret_cast<const float4*>(gs)[lane];
        float4 b4 = reinterpret_cast<const float4*>(bs)[lane];
        ushort4 o;
        o.x = f2bf((v.x-mean)*rstd*g4.x + b4.x);
        o.y = f2bf((v.y-mean)*rstd*g4.y + b4.y);
        o.z = f2bf((v.z-mean)*rstd*g4.z + b4.z);
        o.w = f2bf((v.w-mean)*rstd*g4.w + b4.w);
        *reinterpret_cast<ushort4*>(&sn[rr*264 + lane*4]) = o;
    }
    {
        ushort4 z = {0,0,0,0};
        for (int rr = 8 + wid; rr < 16; rr += 4)
            *reinterpret_cast<ushort4*>(&sn[rr*264 + lane*4]) = z;
    }
    __syncthreads();
    short8 af[8];
#pragma unroll
    for (int k = 0; k < 8; k++) af[k] = *reinterpret_cast<const short8*>(&sn[l15*264 + k*32 + kq]);
#pragma unroll
    for (int ct = 0; ct < 4; ct++) {
        int o0 = (wid*4 + ct)*16;
        f32x4 a = (f32x4){0.f,0.f,0.f,0.f};
#pragma unroll
        for (int k = 0; k < 8; k++) {
            short8 bw = *reinterpret_cast<const short8*>(&wqb[(size_t)(o0 + l15)*256 + k*32 + kq]);
            a = mfma16(af[k], bw, a);
        }
        if (lane < 32) {
            int sb = (lane >> 4)*4;
            float bb = bq[o0 + l15];
#pragma unroll
            for (int r = 0; r < 4; r++)
                qb[(size_t)(b*8 + sb + r)*256 + o0 + l15] = f2bf(a[r] + bb);
        }
    }
}

// ---------------- fused attention pass: barrier-free per-wave streams -------
// 512 blocks (b x 8 segs); wave owns a 128-n strip. NO atomics: per-block
// partials to num_part[b][seg][8][256] / den_part[b][seg][8].
__global__ __launch_bounds__(256) void attn(
        const u16* __restrict__ qb, const u16* __restrict__ kb,
        const u16* __restrict__ vT, float* __restrict__ num_part, float* __restrict__ den_part) {
    __shared__ u16 pb_all[4][16*72];
    const int b = blockIdx.x >> 3;
    const int seg = blockIdx.x & 7;
    const int nseg = seg * 512;
    const int tid = threadIdx.x, wid = tid >> 6, lane = tid & 63;
    const int l15 = lane & 15, quad = lane >> 4, kq = quad * 8;
    u16* pb = pb_all[wid];
    {   // zero P pad rows 8..15 of own wave's buffer
        short8 z = {0,0,0,0,0,0,0,0};
        int r8 = 8 + (lane >> 3), c8 = (lane & 7)*8;
        *reinterpret_cast<short8*>(&pb[r8*72 + c8]) = z;
    }
    // q A-fragment direct from global, rows >=8 zeroed
    short8 aq[8];
    {
        const u16* qrow = &qb[((size_t)b*8 + (l15 & 7))*256 + kq];
        short8 z = {0,0,0,0,0,0,0,0};
#pragma unroll
        for (int kk = 0; kk < 8; kk++) {
            short8 t = *reinterpret_cast<const short8*>(&qrow[kk*32]);
            aq[kk] = (l15 < 8) ? t : z;
        }
    }
    const int n_w = nseg + wid*128;
    const u16* kbase = &kb[((size_t)b*4096 + n_w + l15)*256 + kq];
    const u16* vbase = &vT[((size_t)b*256 + l15)*4096 + n_w + kq];
    f32x4 acc[16];
#pragma unroll
    for (int dt = 0; dt < 16; dt++) acc[dt] = (f32x4){0.f,0.f,0.f,0.f};
    float psum[4] = {0.f,0.f,0.f,0.f};
    short8 kf[8];
#pragma unroll
    for (int kk = 0; kk < 8; kk++) kf[kk] = *reinterpret_cast<const short8*>(&kbase[kk*32]);

    for (int rnd = 0; rnd < 2; rnd++) {
        const int nro = rnd*64;
        f32x4 dots[4];
#pragma unroll
        for (int nt = 0; nt < 4; nt++) {
            short8 kn[8];
            const int next = rnd*4 + nt + 1;
            if (next < 8) {
                const u16* kp = kbase + (size_t)(next*16)*256;
#pragma unroll
                for (int kk = 0; kk < 8; kk++) kn[kk] = *reinterpret_cast<const short8*>(&kp[kk*32]);
            }
            f32x4 d = (f32x4){0.f,0.f,0.f,0.f};
#pragma unroll
            for (int kk = 0; kk < 8; kk++) d = mfma16(aq[kk], kf[kk], d);
            dots[nt] = d;
            if (next < 8) {
#pragma unroll
                for (int kk = 0; kk < 8; kk++) kf[kk] = kn[kk];
            }
        }
        const u16* vr = vbase + nro;
        short8 v0 = *reinterpret_cast<const short8*>(vr);
        short8 v1 = *reinterpret_cast<const short8*>(vr + 32);
#pragma unroll
        for (int nt = 0; nt < 4; nt++) {
            float t0 = dots[nt][0]*0.0625f, t1 = dots[nt][1]*0.0625f;
            float t2 = dots[nt][2]*0.0625f, t3 = dots[nt][3]*0.0625f;
            float m4 = fmaxf(fmaxf(t0,t1), fmaxf(t2,t3));
            float m8 = fmaxf(m4, __shfl_xor(m4, 16, 64));
            float e0 = __expf(t0-m8), e1 = __expf(t1-m8), e2 = __expf(t2-m8), e3 = __expf(t3-m8);
            float s4 = e0+e1+e2+e3;
            float s8 = s4 + __shfl_xor(s4, 16, 64);
            float inv = 1.0f / s8;
            u16 h0 = f2bf(e0*inv + 1e-8f);
            u16 h1 = f2bf(e1*inv + 1e-8f);
            u16 h2 = f2bf(e2*inv + 1e-8f);
            u16 h3 = f2bf(e3*inv + 1e-8f);
            if (lane < 32) {
                int sb = quad*4, col = nt*16 + l15;
                pb[(sb+0)*72 + col] = h0;
                pb[(sb+1)*72 + col] = h1;
                pb[(sb+2)*72 + col] = h2;
                pb[(sb+3)*72 + col] = h3;
                psum[0] += bf2f(h0); psum[1] += bf2f(h1);
                psum[2] += bf2f(h2); psum[3] += bf2f(h3);
            }
        }
        __builtin_amdgcn_s_waitcnt(0xC07F);   // lgkmcnt(0): same-wave p-writes drained
        short8 ap0 = *reinterpret_cast<const short8*>(&pb[l15*72 + kq]);
        short8 ap1 = *reinterpret_cast<const short8*>(&pb[l15*72 + 32 + kq]);
#pragma unroll
        for (int dt = 0; dt < 16; dt++) {
            short8 nv0, nv1;
            if (dt < 15) {
                const u16* vn = vr + (size_t)((dt+1)*16)*4096;
                nv0 = *reinterpret_cast<const short8*>(vn);
                nv1 = *reinterpret_cast<const short8*>(vn + 32);
            }
            acc[dt] = mfma16(ap0, v0, acc[dt]);
            acc[dt] = mfma16(ap1, v1, acc[dt]);
            if (dt < 15) { v0 = nv0; v1 = nv1; }
        }
    }
    // wave-level cross-wave reduction of acc within block? no — each wave has
    // a disjoint n-strip; block partial = sum over 4 waves. Reduce via LDS-free
    // route: each wave writes to its own quarter? Instead: waves accumulate
    // into num_part with disjoint-wave partial layout folded by +: use per-wave
    // smem-free trick -> do block-level sum through LDS reuse of pb_all.
#pragma unroll
    for (int off = 1; off < 16; off <<= 1) {
#pragma unroll
        for (int r = 0; r < 4; r++) psum[r] += __shfl_xor(psum[r], off, 64);
    }
    // block-level reduction across the 4 waves through LDS (f32), then store
    __shared__ float red[4][8][260];
    __shared__ float redd[4][8];
    if (lane < 32) {
        int sb = quad*4;
#pragma unroll
        for (int dt = 0; dt < 16; dt++) {
            int d0 = dt*16 + l15;
#pragma unroll
            for (int r = 0; r < 4; r++)
                red[wid][sb+r][d0] = acc[dt][r];
        }
        if (l15 == 0) {
#pragma unroll
            for (int r = 0; r < 4; r++) redd[wid][sb+r] = psum[r];
        }
    }
    __syncthreads();
    // 256 threads: 8 s-rows x 256 d -> thread handles (s, d) pairs: 2048/256=8
    for (int idx = tid; idx < 2048; idx += 256) {
        int s = idx >> 8, d = idx & 255;
        float v = red[0][s][d] + red[1][s][d] + red[2][s][d] + red[3][s][d];
        num_part[((size_t)(b*8 + seg)*8 + s)*256 + d] = v;
    }
    if (tid < 8)
        den_part[(b*8 + seg)*8 + tid] = redd[0][tid] + redd[1][tid] + redd[2][tid] + redd[3][tid];
}

// ---------------- per-iteration tail: updates -> GRU -> MLP -> slots (+q) ---
__global__ __launch_bounds__(768) void finalize(
        const float* __restrict__ slots_in, const float* __restrict__ num_part, const float* __restrict__ den_part,
        const u16* __restrict__ wihb, const float* __restrict__ bih,
        const u16* __restrict__ whhb, const float* __restrict__ bhh,
        const u16* __restrict__ w1b, const float* __restrict__ b1v,
        const u16* __restrict__ w2b, const float* __restrict__ b2v,
        const float* __restrict__ gff, const float* __restrict__ bff,
        float* __restrict__ slots_out,
        const u16* __restrict__ wqb, const float* __restrict__ bq,
        const float* __restrict__ gs, const float* __restrict__ bs,
        u16* __restrict__ qb, int do_q) {
    __shared__ u16 updb[16*264];
    __shared__ u16 prevb[16*264];
    __shared__ u16 lnb[16*264];
    __shared__ float gx[8*776];
    __shared__ float gh[8*776];
    __shared__ float snew[8*256];
    __shared__ float dsum_s[8];
    float* sfin = gx;    // reuse after gates consumed
    const int b = blockIdx.x;
    const int tid = threadIdx.x, wid = tid >> 6, lane = tid & 63;
    const int l15 = lane & 15, kq = (lane >> 4) * 8;
    if (tid < 8) {
        float ds = 0.f;
#pragma unroll
        for (int sg = 0; sg < 8; sg++) ds += den_part[(b*8 + sg)*8 + tid];
        dsum_s[tid] = ds;
    }
    __syncthreads();
    for (int idx = tid; idx < 2048; idx += 768) {
        int s = idx >> 8, d = idx & 255;
        float ns = 0.f;
#pragma unroll
        for (int sg = 0; sg < 8; sg++)
            ns += num_part[((size_t)(b*8 + sg)*8 + s)*256 + d];
        updb[s*264 + d] = f2bf(ns / dsum_s[s]);
        prevb[s*264 + d] = f2bf(slots_in[(size_t)(b*8 + s)*256 + d]);
        updb[(8+s)*264 + d] = 0;
        prevb[(8+s)*264 + d] = 0;
    }
    __syncthreads();
    short8 au[8], ap[8];
#pragma unroll
    for (int k = 0; k < 8; k++) {
        au[k] = *reinterpret_cast<const short8*>(&updb[l15*264 + k*32 + kq]);
        ap[k] = *reinterpret_cast<const short8*>(&prevb[l15*264 + k*32 + kq]);
    }
#pragma unroll
    for (int ct = 0; ct < 4; ct++) {
        int o0 = (wid*4 + ct)*16;
        f32x4 ax = (f32x4){0.f,0.f,0.f,0.f}, ah = (f32x4){0.f,0.f,0.f,0.f};
#pragma unroll
        for (int k = 0; k < 8; k++) {
            short8 bx = *reinterpret_cast<const short8*>(&wihb[(size_t)(o0 + l15)*256 + k*32 + kq]);
            short8 bh = *reinterpret_cast<const short8*>(&whhb[(size_t)(o0 + l15)*256 + k*32 + kq]);
            ax = mfma16(au[k], bx, ax);
            ah = mfma16(ap[k], bh, ah);
        }
        if (lane < 32) {
            int sb = (lane >> 4)*4, o = o0 + l15;
            float bxs = bih[o], bhs = bhh[o];
#pragma unroll
            for (int r = 0; r < 4; r++) {
                gx[(sb+r)*776 + o] = ax[r] + bxs;
                gh[(sb+r)*776 + o] = ah[r] + bhs;
            }
        }
    }
    __syncthreads();
    for (int idx = tid; idx < 2048; idx += 768) {
        int s = idx >> 8, j = idx & 255;
        float xr = gx[s*776 + j], xz = gx[s*776 + 256 + j], xn = gx[s*776 + 512 + j];
        float hr = gh[s*776 + j], hz = gh[s*776 + 256 + j], hn = gh[s*776 + 512 + j];
        float r_ = 1.f/(1.f + __expf(-(xr+hr)));
        float z_ = 1.f/(1.f + __expf(-(xz+hz)));
        float n_ = tanhf(xn + r_*hn);
        float pv = slots_in[(size_t)(b*8 + s)*256 + j];
        snew[s*256 + j] = (1.f - z_)*n_ + z_*pv;
    }
    __syncthreads();
    if (wid < 8) {
        int rr = wid;
        float4 v = reinterpret_cast<const float4*>(&snew[rr*256])[lane];
        float s = v.x + v.y + v.z + v.w;
        float ss = v.x*v.x + v.y*v.y + v.z*v.z + v.w*v.w;
#pragma unroll
        for (int off = 32; off >= 1; off >>= 1) { s += __shfl_xor(s, off, 64); ss += __shfl_xor(ss, off, 64); }
        float mean = s * (1.f/256.f);
        float rstd = rsqrtf(ss * (1.f/256.f) - mean*mean + 1e-5f);
        float4 g4 = reinterpret_cast<const float4*>(gff)[lane];
        float4 b4 = reinterpret_cast<const float4*>(bff)[lane];
        ushort4 o;
        o.x = f2bf((v.x-mean)*rstd*g4.x + b4.x);
        o.y = f2bf((v.y-mean)*rstd*g4.y + b4.y);
        o.z = f2bf((v.z-mean)*rstd*g4.z + b4.z);
        o.w = f2bf((v.w-mean)*rstd*g4.w + b4.w);
        *reinterpret_cast<ushort4*>(&lnb[rr*264 + lane*4]) = o;
    } else {
        ushort4 z = {0,0,0,0};
        *reinterpret_cast<ushort4*>(&lnb[wid*264 + lane*4]) = z;
        *reinterpret_cast<ushort4*>(&lnb[(wid+4)*264 + lane*4]) = z;
    }
    __syncthreads();
    short8 al[8];
#pragma unroll
    for (int k = 0; k < 8; k++) al[k] = *reinterpret_cast<const short8*>(&lnb[l15*264 + k*32 + kq]);
    for (int ct = wid; ct < 16; ct += 12) {
        int o0 = ct*16;
        f32x4 a = (f32x4){0.f,0.f,0.f,0.f};
#pragma unroll
        for (int k = 0; k < 8; k++) {
            short8 bw = *reinterpret_cast<const short8*>(&w1b[(size_t)(o0 + l15)*256 + k*32 + kq]);
            a = mfma16(al[k], bw, a);
        }
        if (lane < 32) {
            int sb = (lane >> 4)*4, o = o0 + l15;
            float bb = b1v[o];
#pragma unroll
            for (int r = 0; r < 4; r++)
                updb[(sb+r)*264 + o] = f2bf(fmaxf(a[r] + bb, 0.f));
        }
    }
    __syncthreads();
    short8 ah2[8];
#pragma unroll
    for (int k = 0; k < 8; k++) ah2[k] = *reinterpret_cast<const short8*>(&updb[l15*264 + k*32 + kq]);
    for (int ct = wid; ct < 16; ct += 12) {
        int o0 = ct*16;
        f32x4 a = (f32x4){0.f,0.f,0.f,0.f};
#pragma unroll
        for (int k = 0; k < 8; k++) {
            short8 bw = *reinterpret_cast<const short8*>(&w2b[(size_t)(o0 + l15)*256 + k*32 + kq]);
            a = mfma16(ah2[k], bw, a);
        }
        if (lane < 32) {
            int sb = (lane >> 4)*4, o = o0 + l15;
            float bb = b2v[o];
#pragma unroll
            for (int r = 0; r < 4; r++) {
                float vfin = snew[(sb+r)*256 + o] + a[r] + bb;
                slots_out[(size_t)(b*8 + sb + r)*256 + o] = vfin;
                sfin[(sb+r)*256 + o] = vfin;
            }
        }
    }
    if (!do_q) return;
    __syncthreads();
    // fused q projection for next iteration: q = LN(slots_new)@wq^T + bq
    if (wid < 8) {
        int rr = wid;
        float4 v = reinterpret_cast<const float4*>(&sfin[rr*256])[lane];
        float s = v.x + v.y + v.z + v.w;
        float ss = v.x*v.x + v.y*v.y + v.z*v.z + v.w*v.w;
#pragma unroll
        for (int off = 32; off >= 1; off >>= 1) { s += __shfl_xor(s, off, 64); ss += __shfl_xor(ss, off, 64); }
        float mean = s * (1.f/256.f);
        float rstd = rsqrtf(ss * (1.f/256.f) - mean*mean + 1e-5f);
        float4 g4 = reinterpret_cast<const float4*>(gs)[lane];
        float4 b4 = reinterpret_cast<const float4*>(bs)[lane];
        ushort4 o;
        o.x = f2bf((v.x-mean)*rstd*g4.x + b4.x);
        o.y = f2bf((v.y-mean)*rstd*g4.y + b4.y);
        o.z = f2bf((v.z-mean)*rstd*g4.z + b4.z);
        o.w = f2bf((v.w-mean)*rstd*g4.w + b4.w);
        *reinterpret_cast<ushort4*>(&lnb[rr*264 + lane*4]) = o;
    } else {
        ushort4 z = {0,0,0,0};
        *reinterpret_cast<ushort4*>(&lnb[wid*264 + lane*4]) = z;
        *reinterpret_cast<ushort4*>(&lnb[(wid+4)*264 + lane*4]) = z;
    }
    __syncthreads();
    short8 alq[8];
#pragma unroll
    for (int k = 0; k < 8; k++) alq[k] = *reinterpret_cast<const short8*>(&lnb[l15*264 + k*32 + kq]);
    for (int ct = wid; ct < 16; ct += 12) {
        int o0 = ct*16;
        f32x4 a = (f32x4){0.f,0.f,0.f,0.f};
#pragma unroll
        for (int k = 0; k < 8; k++) {
            short8 bw = *reinterpret_cast<const short8*>(&wqb[(size_t)(o0 + l15)*256 + k*32 + kq]);
            a = mfma16(alq[k], bw, a);
        }
        if (lane < 32) {
            int sb = (lane >> 4)*4, o = o0 + l15;
            float bb = bq[o];
#pragma unroll
            for (int r = 0; r < 4; r++)
                qb[(size_t)(b*8 + sb + r)*256 + o] = f2bf(a[r] + bb);
        }
    }
}

extern "C" void kernel_launch(void* const* d_in, const int* in_sizes, int n_in,
                              void* d_out, int out_size, void* d_ws, size_t ws_size,
                              hipStream_t stream) {
    (void)in_sizes; (void)n_in; (void)out_size;
    const float* inputs     = (const float*)d_in[0];
    const float* init_slots = (const float*)d_in[1];
    const float* wq  = (const float*)d_in[2];
    const float* bq  = (const float*)d_in[3];
    const float* wk  = (const float*)d_in[4];
    const float* bk  = (const float*)d_in[5];
    const float* wv  = (const float*)d_in[6];
    const float* bv  = (const float*)d_in[7];
    const float* wih = (const float*)d_in[8];
    const float* bih = (const float*)d_in[9];
    const float* whh = (const float*)d_in[10];
    const float* bhh = (const float*)d_in[11];
    const float* w1  = (const float*)d_in[12];
    const float* b1  = (const float*)d_in[13];
    const float* w2  = (const float*)d_in[14];
    const float* b2  = (const float*)d_in[15];
    const float* g_in = (const float*)d_in[16];
    const float* b_in = (const float*)d_in[17];
    const float* g_sl = (const float*)d_in[18];
    const float* b_sl = (const float*)d_in[19];
    const float* g_ff = (const float*)d_in[20];
    const float* b_ff = (const float*)d_in[21];

    char* ws = (char*)d_ws;
    size_t off = 0;
    auto alloc = [&](size_t bytes) -> void* {
        void* p = ws + off;
        off += (bytes + 255) & ~(size_t)255;
        return p;
    };
    u16* kbf   = (u16*)alloc((size_t)GROWS * ND * 2);   // k bf16 [b][n][d]
    u16* vTb   = (u16*)alloc((size_t)GROWS * ND * 2);   // v bf16 transposed [b][d][n]
    u16* qbf   = (u16*)alloc((size_t)NB * NS * ND * 2);
    float* slots = (float*)alloc((size_t)NB * NS * ND * 4);
    float* nump  = (float*)alloc((size_t)NB * 8 * NS * ND * 4);  // per-seg partials
    float* denp  = (float*)alloc((size_t)NB * 8 * NS * 4);
    u16* wkvb = (u16*)alloc(131072 * 2);
    u16* wqb  = (u16*)alloc(65536 * 2);
    u16* wihb = (u16*)alloc(196608 * 2);
    u16* whhb = (u16*)alloc(196608 * 2);
    u16* w1b  = (u16*)alloc(65536 * 2);
    u16* w2b  = (u16*)alloc(65536 * 2);
    if (off > ws_size) return;  // insufficient workspace -> visible failure

    prep_w<<<2816, 256, 0, stream>>>(wk, wv, wq, wih, whh, w1, w2,
                                     wkvb, wqb, wihb, whhb, w1b, w2b);
    hipMemcpyAsync(slots, init_slots, (size_t)NB * NS * ND * 4,
                   hipMemcpyDeviceToDevice, stream);
    ln_gemm_kv<<<GROWS / 64, 256, 0, stream>>>(inputs, g_in, b_in, wkvb, bk, bv, kbf, vTb);
    q_proj<<<NB, 256, 0, stream>>>(slots, wqb, bq, g_sl, b_sl, qbf);
    for (int it = 0; it < 3; it++) {
        attn<<<NB * 8, 256, 0, stream>>>(qbf, kbf, vTb, nump, denp);
        float* outp = (it == 2) ? (float*)d_out : slots;
        finalize<<<NB, 768, 0, stream>>>(slots, nump, denp, wihb, bih, whhb, bhh,
                                         w1b, b1, w2b, b2, g_ff, b_ff, outp,
                                         wqb, bq, g_sl, b_sl, qbf, (it < 2) ? 1 : 0);
    }
}